// Round 4
// baseline (350.733 us; speedup 1.0000x reference)
//
#include <hip/hip_runtime.h>
#include <cstdint>
#include <cstddef>

typedef __bf16 bf16_t;
typedef __bf16 bf16x4 __attribute__((ext_vector_type(4)));
typedef __bf16 bf16x8 __attribute__((ext_vector_type(8)));
typedef float  f32x4  __attribute__((ext_vector_type(4)));

#define LDQ 3072   // QKV buffer row stride (elements)

// ---------------- cast f32 -> bf16, 8 elems/thread ----------------
__global__ __launch_bounds__(256)
void cast_kernel(const float* __restrict__ in, bf16_t* __restrict__ out, int n8) {
  int i = blockIdx.x * 256 + threadIdx.x;
  if (i >= n8) return;
  const float4* p = reinterpret_cast<const float4*>(in) + (size_t)i * 2;
  float4 a = p[0], b = p[1];
  bf16x8 o;
  o[0] = (bf16_t)a.x; o[1] = (bf16_t)a.y; o[2] = (bf16_t)a.z; o[3] = (bf16_t)a.w;
  o[4] = (bf16_t)b.x; o[5] = (bf16_t)b.y; o[6] = (bf16_t)b.z; o[7] = (bf16_t)b.w;
  *reinterpret_cast<bf16x8*>(out + (size_t)i * 8) = o;
}

// ---------------- GEMM: C[M,N] = A[M,K] * B[N,K]^T + bias ----------------
// MODE 1 scales the Q section (cols<2048) by log2(e)/sqrt(128).
template <int MODE>
__global__ __launch_bounds__(256)
void gemm_bt(const bf16_t* __restrict__ A, const bf16_t* __restrict__ B,
             const float* __restrict__ bias0, const float* __restrict__ bias1,
             void* __restrict__ out0, float* __restrict__ kvout,
             bf16_t* __restrict__ vt, int M, int N, int K) {
  __shared__ __align__(16) bf16_t As[128][64];
  __shared__ __align__(16) bf16_t Bs[128][64];
  const int t = threadIdx.x;
  const int l = t & 63, w = t >> 6;
  const int lr = l & 15, lh = l >> 4;
  const int m0 = blockIdx.x * 128, n0 = blockIdx.y * 128;
  const int wm = (w >> 1) * 64, wn = (w & 1) * 64;

  f32x4 acc[4][4] = {};

  for (int kt = 0; kt < K; kt += 64) {
    #pragma unroll
    for (int it = 0; it < 4; ++it) {
      int e = (it * 256 + t) * 8;
      int row = e >> 6, col = e & 63;
      __builtin_amdgcn_global_load_lds(
          (const __attribute__((address_space(1))) void*)(A + (size_t)(m0 + row) * K + kt + col),
          (__attribute__((address_space(3))) void*)(&As[row][col]), 16, 0, 0);
      __builtin_amdgcn_global_load_lds(
          (const __attribute__((address_space(1))) void*)(B + (size_t)(n0 + row) * K + kt + col),
          (__attribute__((address_space(3))) void*)(&Bs[row][col]), 16, 0, 0);
    }
    __syncthreads();
    #pragma unroll
    for (int ks = 0; ks < 2; ++ks) {
      bf16x8 a[4], b[4];
      #pragma unroll
      for (int i = 0; i < 4; ++i)
        a[i] = *reinterpret_cast<const bf16x8*>(&As[wm + i * 16 + lr][ks * 32 + lh * 8]);
      #pragma unroll
      for (int j = 0; j < 4; ++j)
        b[j] = *reinterpret_cast<const bf16x8*>(&Bs[wn + j * 16 + lr][ks * 32 + lh * 8]);
      #pragma unroll
      for (int i = 0; i < 4; ++i)
        #pragma unroll
        for (int j = 0; j < 4; ++j)
          acc[i][j] = __builtin_amdgcn_mfma_f32_16x16x32_bf16(a[i], b[j], acc[i][j], 0, 0, 0);
    }
    __syncthreads();
  }

  #pragma unroll
  for (int j = 0; j < 4; ++j) {
    const int col = n0 + wn + j * 16 + lr;
    float bv;
    if constexpr (MODE == 0) bv = bias0[col];
    else bv = (col < 2048) ? bias0[col] : bias1[col - 2048];
    #pragma unroll
    for (int i = 0; i < 4; ++i) {
      #pragma unroll
      for (int r = 0; r < 4; ++r) {
        const int row = m0 + wm + i * 16 + lh * 4 + r;
        float v = acc[i][j][r] + bv;
        if constexpr (MODE == 0) {
          reinterpret_cast<float*>(out0)[(size_t)row * N + col] = v;
        } else {
          float qv = (col < 2048) ? v * 0.1275187541f : v;
          reinterpret_cast<bf16_t*>(out0)[(size_t)row * N + col] = (bf16_t)qv;
          if (col >= 2048) {
            const int local = col - 2048;
            const int which = local >> 9;
            const int hd    = local & 511;
            kvout[(size_t)which * 2097152 +
                  ((size_t)(hd >> 7) * 4096 + row) * 128 + (hd & 127)] = v;
            if (local >= 512) {
              const int c2 = local - 512;
              vt[(size_t)(c2 >> 7) * 524288 + (size_t)(c2 & 127) * 4096 + row] = (bf16_t)v;
            }
          }
        }
      }
    }
  }
}

// ---------------- causal GQA flash attention, in-register P ----------------
// grid (32, 16): 4 waves x 32 q-rows = 128 q/block, KV tile 64, K+V double-buffered.
// Swapped QK (mfma(K,Q)) puts P[q=lr][key] in-lane -> PV A-operand直接, no P LDS.
__global__ __launch_bounds__(256, 2)
void attn_kernel(const bf16_t* __restrict__ QKVb, const bf16_t* __restrict__ Vt,
                 bf16_t* __restrict__ Ob) {
  __shared__ __align__(16) bf16_t Ks[2][64 * 128];   // swizzled K tiles (256B rows)
  __shared__ __align__(16) bf16_t Vs[2][128 * 64];   // swizzled V^T tiles (128B rows)
  const int t = threadIdx.x;
  const int w = t >> 6, l = t & 63;
  const int lr = l & 15, lh = l >> 4;
  const int h = blockIdx.y, kvh = h >> 2;
  const int q0b = ((int)gridDim.x - 1 - (int)blockIdx.x) * 128;  // largest first
  const int q0w = q0b + w * 32;
  const int nIter = q0b / 64 + 2;

  const char* Kg = (const char*)(QKVb + 2048 + (size_t)kvh * 128);  // row 6144 B
  const char* Vg = (const char*)(Vt + (size_t)kvh * 524288);        // row 8192 B

#define STAGE_K(buf, kv0)                                                          \
  {                                                                                \
    _Pragma("unroll")                                                              \
    for (int p = 0; p < 4; ++p) {                                                  \
      int chunk = p * 256 + t;                                                     \
      int row = chunk >> 4, cb = (chunk & 15) << 4;                                \
      __builtin_amdgcn_global_load_lds(                                            \
        (const __attribute__((address_space(1))) void*)                            \
            (Kg + (size_t)((kv0) + row) * 6144 + (cb ^ ((row & 7) << 4))),         \
        (__attribute__((address_space(3))) void*)((char*)&Ks[buf][0] + chunk * 16),\
        16, 0, 0);                                                                 \
    }                                                                              \
  }
#define STAGE_V(buf, kv0)                                                          \
  {                                                                                \
    _Pragma("unroll")                                                              \
    for (int p = 0; p < 4; ++p) {                                                  \
      int chunk = p * 256 + t;                                                     \
      int row = chunk >> 3, cb = (chunk & 7) << 4;                                 \
      __builtin_amdgcn_global_load_lds(                                            \
        (const __attribute__((address_space(1))) void*)                            \
            (Vg + (size_t)row * 8192 + (size_t)(kv0) * 2 + (cb ^ ((row & 7) << 4))),\
        (__attribute__((address_space(3))) void*)((char*)&Vs[buf][0] + chunk * 16),\
        16, 0, 0);                                                                 \
    }                                                                              \
  }

  // Q fragments first (their vmcnt drains under the first tile wait)
  bf16x8 qf[2][4];
  #pragma unroll
  for (int sub = 0; sub < 2; ++sub) {
    const bf16_t* qp = QKVb + (size_t)(q0w + sub * 16 + lr) * LDQ + h * 128 + lh * 8;
    #pragma unroll
    for (int kc = 0; kc < 4; ++kc) qf[sub][kc] = *reinterpret_cast<const bf16x8*>(qp + kc * 32);
  }

  STAGE_K(0, 0);
  STAGE_V(0, 0);
  STAGE_K(1, 64);     // nIter >= 2 always
  STAGE_V(1, 64);

  f32x4 oacc[2][8] = {};
  float lsum[2] = {0.f, 0.f};

  for (int it = 0; it < nIter; ++it) {
    const int cur = it & 1;
    const int kv0 = it * 64;
    // tile it must be resident; tile it+1 (8 loads) may stay in flight (T4)
    if (it + 1 < nIter) { asm volatile("s_waitcnt vmcnt(8)" ::: "memory"); }
    else                { asm volatile("s_waitcnt vmcnt(0)" ::: "memory"); }
    __builtin_amdgcn_s_barrier();
    __builtin_amdgcn_sched_barrier(0);

    // ---- S^T = K Q^T : lane holds S[q=lr][key=kv0+n*16+lh*4+r] ----
    const char* kb = (const char*)&Ks[cur][0];
    f32x4 s0[4] = {}, s1[4] = {};
    __builtin_amdgcn_s_setprio(1);
    #pragma unroll
    for (int n = 0; n < 4; ++n) {
      const int row = n * 16 + lr;
      const int sw = (row & 7) << 4;
      #pragma unroll
      for (int kc = 0; kc < 4; ++kc) {
        bf16x8 kf = *reinterpret_cast<const bf16x8*>(kb + row * 256 + ((kc * 64 + lh * 16) ^ sw));
        s0[n] = __builtin_amdgcn_mfma_f32_16x16x32_bf16(kf, qf[0][kc], s0[n], 0, 0, 0);
        s1[n] = __builtin_amdgcn_mfma_f32_16x16x32_bf16(kf, qf[1][kc], s1[n], 0, 0, 0);
      }
    }
    __builtin_amdgcn_s_setprio(0);

    // ---- P = exp2(S) in registers, packed as PV A-fragments ----
    // k-map for PV MFMA kc2: elements 0-3 <- n=2*kc2 (keys +lh*4+r), 4-7 <- n=2*kc2+1
    bf16x8 pa[2][2];
    #pragma unroll
    for (int sub = 0; sub < 2; ++sub) {
      const int qs = q0w + sub * 16;
      const bool needM = (kv0 + 63 > qs);
      #pragma unroll
      for (int kc2 = 0; kc2 < 2; ++kc2) {
        bf16x8 v;
        #pragma unroll
        for (int half = 0; half < 2; ++half) {
          const int n = kc2 * 2 + half;
          f32x4 sv = sub ? s1[n] : s0[n];
          #pragma unroll
          for (int r = 0; r < 4; ++r) {
            float p = exp2f(sv[r]);
            if (needM && (kv0 + n * 16 + lh * 4 + r > qs + lr)) p = 0.f;
            lsum[sub] += p;
            v[half * 4 + r] = (bf16_t)p;
          }
        }
        pa[sub][kc2] = v;
      }
    }

    // ---- O += P V : B-frag = V^T rows (d), two b64 reads per fragment ----
    const char* vb0 = (const char*)&Vs[cur][0];
    __builtin_amdgcn_s_setprio(1);
    #pragma unroll
    for (int kc2 = 0; kc2 < 2; ++kc2) {
      #pragma unroll
      for (int nb = 0; nb < 8; ++nb) {
        const int row = nb * 16 + lr;
        const int sw2 = (row & 7) << 4;
        const char* vb = vb0 + row * 128;
        bf16x4 lo = *reinterpret_cast<const bf16x4*>(vb + ((kc2 * 64 + lh * 8) ^ sw2));
        bf16x4 hi = *reinterpret_cast<const bf16x4*>(vb + ((kc2 * 64 + 32 + lh * 8) ^ sw2));
        bf16x8 vf = __builtin_shufflevector(lo, hi, 0, 1, 2, 3, 4, 5, 6, 7);
        oacc[0][nb] = __builtin_amdgcn_mfma_f32_16x16x32_bf16(pa[0][kc2], vf, oacc[0][nb], 0, 0, 0);
        oacc[1][nb] = __builtin_amdgcn_mfma_f32_16x16x32_bf16(pa[1][kc2], vf, oacc[1][nb], 0, 0, 0);
      }
    }
    __builtin_amdgcn_s_setprio(0);

    // ---- all waves done reading buf cur -> refill it for tile it+2 ----
    __builtin_amdgcn_sched_barrier(0);
    __builtin_amdgcn_s_barrier();
    __builtin_amdgcn_sched_barrier(0);
    if (it + 2 < nIter) { STAGE_K(cur, kv0 + 128); STAGE_V(cur, kv0 + 128); }
  }

  // ---- row sums: lane partial covers its (lh,r,n) keys; fold lh groups ----
  #pragma unroll
  for (int sub = 0; sub < 2; ++sub) {
    float s = lsum[sub];
    s += __shfl_xor(s, 16);
    s += __shfl_xor(s, 32);     // lane now holds full sum for q = qs + lr
    f32x4 linv;
    #pragma unroll
    for (int r = 0; r < 4; ++r) linv[r] = 1.0f / __shfl(s, lh * 4 + r);
    #pragma unroll
    for (int nb = 0; nb < 8; ++nb) {
      #pragma unroll
      for (int r = 0; r < 4; ++r) {
        float v = oacc[sub][nb][r] * linv[r];
        Ob[(size_t)(q0w + sub * 16 + lh * 4 + r) * 2048 + h * 128 + nb * 16 + lr] = (bf16_t)v;
      }
    }
  }
#undef STAGE_K
#undef STAGE_V
}

extern "C" void kernel_launch(void* const* d_in, const int* in_sizes, int n_in,
                              void* d_out, int out_size, void* d_ws, size_t ws_size,
                              hipStream_t stream) {
  const float* seq   = (const float*)d_in[0];
  const float* Wq_w  = (const float*)d_in[2];
  const float* Wq_b  = (const float*)d_in[3];
  const float* Wkv_w = (const float*)d_in[4];
  const float* Wkv_b = (const float*)d_in[5];
  const float* Wo_w  = (const float*)d_in[6];
  const float* Wo_b  = (const float*)d_in[7];

  float* out   = (float*)d_out;
  float* kvout = out + (size_t)4096 * 2048;

  char* ws = (char*)d_ws;
  bf16_t* seqb = (bf16_t*)ws;                          // [4096][2048] (reused as Ob)
  bf16_t* wqkv = (bf16_t*)(ws + 16777216);             // [3072][2048]
  bf16_t* wob  = (bf16_t*)(ws + 29360128);             // [2048][2048]
  bf16_t* qkvb = (bf16_t*)(ws + 37748736);             // [4096][3072]
  bf16_t* vt   = (bf16_t*)(ws + 62914560);             // [4][128][4096]
  bf16_t* ob   = seqb;

  cast_kernel<<<4096, 256, 0, stream>>>(seq, seqb, 1048576);
  cast_kernel<<<2048, 256, 0, stream>>>(Wq_w, wqkv, 524288);
  cast_kernel<<<1024, 256, 0, stream>>>(Wkv_w, wqkv + 4194304, 262144);
  cast_kernel<<<2048, 256, 0, stream>>>(Wo_w, wob, 524288);

  gemm_bt<1><<<dim3(32, 24), 256, 0, stream>>>(seqb, wqkv, Wq_b, Wkv_b,
                                               qkvb, kvout, vt, 4096, 3072, 2048);
  attn_kernel<<<dim3(32, 16), 256, 0, stream>>>(qkvb, vt, ob);
  gemm_bt<0><<<dim3(32, 16), 256, 0, stream>>>(ob, wob, Wo_b, nullptr,
                                               out, nullptr, nullptr, 4096, 2048, 2048);
}

// Round 5
// 321.586 us; speedup vs baseline: 1.0906x; 1.0906x over previous
//
#include <hip/hip_runtime.h>
#include <cstdint>
#include <cstddef>

typedef __bf16 bf16_t;
typedef __bf16 bf16x4 __attribute__((ext_vector_type(4)));
typedef __bf16 bf16x8 __attribute__((ext_vector_type(8)));
typedef float  f32x4  __attribute__((ext_vector_type(4)));

#define LDQ 3072   // QKV buffer row stride (elements)

// ---------------- cast f32 -> bf16, 8 elems/thread ----------------
__global__ __launch_bounds__(256)
void cast_kernel(const float* __restrict__ in, bf16_t* __restrict__ out, int n8) {
  int i = blockIdx.x * 256 + threadIdx.x;
  if (i >= n8) return;
  const float4* p = reinterpret_cast<const float4*>(in) + (size_t)i * 2;
  float4 a = p[0], b = p[1];
  bf16x8 o;
  o[0] = (bf16_t)a.x; o[1] = (bf16_t)a.y; o[2] = (bf16_t)a.z; o[3] = (bf16_t)a.w;
  o[4] = (bf16_t)b.x; o[5] = (bf16_t)b.y; o[6] = (bf16_t)b.z; o[7] = (bf16_t)b.w;
  *reinterpret_cast<bf16x8*>(out + (size_t)i * 8) = o;
}

// ---------------- GEMM: C[M,N] = A[M,K] * B[N,K]^T + bias ----------------
// MODE 1 scales the Q section (cols<2048) by log2(e)/sqrt(128).
template <int MODE>
__global__ __launch_bounds__(256)
void gemm_bt(const bf16_t* __restrict__ A, const bf16_t* __restrict__ B,
             const float* __restrict__ bias0, const float* __restrict__ bias1,
             void* __restrict__ out0, float* __restrict__ kvout,
             bf16_t* __restrict__ vt, int M, int N, int K) {
  __shared__ __align__(16) bf16_t As[128][64];
  __shared__ __align__(16) bf16_t Bs[128][64];
  const int t = threadIdx.x;
  const int l = t & 63, w = t >> 6;
  const int lr = l & 15, lh = l >> 4;
  const int m0 = blockIdx.x * 128, n0 = blockIdx.y * 128;
  const int wm = (w >> 1) * 64, wn = (w & 1) * 64;

  f32x4 acc[4][4] = {};

  for (int kt = 0; kt < K; kt += 64) {
    #pragma unroll
    for (int it = 0; it < 4; ++it) {
      int e = (it * 256 + t) * 8;
      int row = e >> 6, col = e & 63;
      __builtin_amdgcn_global_load_lds(
          (const __attribute__((address_space(1))) void*)(A + (size_t)(m0 + row) * K + kt + col),
          (__attribute__((address_space(3))) void*)(&As[row][col]), 16, 0, 0);
      __builtin_amdgcn_global_load_lds(
          (const __attribute__((address_space(1))) void*)(B + (size_t)(n0 + row) * K + kt + col),
          (__attribute__((address_space(3))) void*)(&Bs[row][col]), 16, 0, 0);
    }
    __syncthreads();
    #pragma unroll
    for (int ks = 0; ks < 2; ++ks) {
      bf16x8 a[4], b[4];
      #pragma unroll
      for (int i = 0; i < 4; ++i)
        a[i] = *reinterpret_cast<const bf16x8*>(&As[wm + i * 16 + lr][ks * 32 + lh * 8]);
      #pragma unroll
      for (int j = 0; j < 4; ++j)
        b[j] = *reinterpret_cast<const bf16x8*>(&Bs[wn + j * 16 + lr][ks * 32 + lh * 8]);
      #pragma unroll
      for (int i = 0; i < 4; ++i)
        #pragma unroll
        for (int j = 0; j < 4; ++j)
          acc[i][j] = __builtin_amdgcn_mfma_f32_16x16x32_bf16(a[i], b[j], acc[i][j], 0, 0, 0);
    }
    __syncthreads();
  }

  #pragma unroll
  for (int j = 0; j < 4; ++j) {
    const int col = n0 + wn + j * 16 + lr;
    float bv;
    if constexpr (MODE == 0) bv = bias0[col];
    else bv = (col < 2048) ? bias0[col] : bias1[col - 2048];
    #pragma unroll
    for (int i = 0; i < 4; ++i) {
      #pragma unroll
      for (int r = 0; r < 4; ++r) {
        const int row = m0 + wm + i * 16 + lh * 4 + r;
        float v = acc[i][j][r] + bv;
        if constexpr (MODE == 0) {
          reinterpret_cast<float*>(out0)[(size_t)row * N + col] = v;
        } else {
          float qv = (col < 2048) ? v * 0.1275187541f : v;
          reinterpret_cast<bf16_t*>(out0)[(size_t)row * N + col] = (bf16_t)qv;
          if (col >= 2048) {
            const int local = col - 2048;
            const int which = local >> 9;
            const int hd    = local & 511;
            kvout[(size_t)which * 2097152 +
                  ((size_t)(hd >> 7) * 4096 + row) * 128 + (hd & 127)] = v;
            if (local >= 512) {
              const int c2 = local - 512;
              vt[(size_t)(c2 >> 7) * 524288 + (size_t)(c2 & 127) * 4096 + row] = (bf16_t)v;
            }
          }
        }
      }
    }
  }
}

// ---------------- causal GQA flash attention, in-register P ----------------
// grid (32, 16): 4 waves x 32 q-rows = 128 q/block, KV tile 64, K+V double-buffered.
// q-tile remap (y&8 ? x : 31-x) pairs complementary causal depths on each CU:
// blocks b and b+256 (same x, y^8) sum to a constant 66 tile-iters -> balanced.
__global__ __launch_bounds__(256, 2)
void attn_kernel(const bf16_t* __restrict__ QKVb, const bf16_t* __restrict__ Vt,
                 bf16_t* __restrict__ Ob) {
  __shared__ __align__(16) bf16_t Ks[2][64 * 128];   // swizzled K tiles (256B rows)
  __shared__ __align__(16) bf16_t Vs[2][128 * 64];   // swizzled V^T tiles (128B rows)
  const int t = threadIdx.x;
  const int w = t >> 6, l = t & 63;
  const int lr = l & 15, lh = l >> 4;
  const int h = blockIdx.y, kvh = h >> 2;
  const int T = (blockIdx.y & 8) ? (int)blockIdx.x : 31 - (int)blockIdx.x;
  const int q0b = T * 128;
  const int q0w = q0b + w * 32;
  const int nIter = 2 * T + 2;

  const char* Kg = (const char*)(QKVb + 2048 + (size_t)kvh * 128);  // row 6144 B
  const char* Vg = (const char*)(Vt + (size_t)kvh * 524288);        // row 8192 B

#define STAGE_K(buf, kv0)                                                          \
  {                                                                                \
    _Pragma("unroll")                                                              \
    for (int p = 0; p < 4; ++p) {                                                  \
      int chunk = p * 256 + t;                                                     \
      int row = chunk >> 4, cb = (chunk & 15) << 4;                                \
      __builtin_amdgcn_global_load_lds(                                            \
        (const __attribute__((address_space(1))) void*)                            \
            (Kg + (size_t)((kv0) + row) * 6144 + (cb ^ ((row & 7) << 4))),         \
        (__attribute__((address_space(3))) void*)((char*)&Ks[buf][0] + chunk * 16),\
        16, 0, 0);                                                                 \
    }                                                                              \
  }
#define STAGE_V(buf, kv0)                                                          \
  {                                                                                \
    _Pragma("unroll")                                                              \
    for (int p = 0; p < 4; ++p) {                                                  \
      int chunk = p * 256 + t;                                                     \
      int row = chunk >> 3, cb = (chunk & 7) << 4;                                 \
      __builtin_amdgcn_global_load_lds(                                            \
        (const __attribute__((address_space(1))) void*)                            \
            (Vg + (size_t)row * 8192 + (size_t)(kv0) * 2 + (cb ^ ((row & 7) << 4))),\
        (__attribute__((address_space(3))) void*)((char*)&Vs[buf][0] + chunk * 16),\
        16, 0, 0);                                                                 \
    }                                                                              \
  }

  // Q fragments first (their vmcnt drains under the first tile wait)
  bf16x8 qf[2][4];
  #pragma unroll
  for (int sub = 0; sub < 2; ++sub) {
    const bf16_t* qp = QKVb + (size_t)(q0w + sub * 16 + lr) * LDQ + h * 128 + lh * 8;
    #pragma unroll
    for (int kc = 0; kc < 4; ++kc) qf[sub][kc] = *reinterpret_cast<const bf16x8*>(qp + kc * 32);
  }

  STAGE_K(0, 0);
  STAGE_V(0, 0);
  STAGE_K(1, 64);     // nIter >= 2 always
  STAGE_V(1, 64);

  f32x4 oacc[2][8] = {};
  f32x4 lsum4[2] = {};

  for (int it = 0; it < nIter; ++it) {
    const int cur = it & 1;
    const int kv0 = it * 64;
    // tile it must be resident; tile it+1 (8 loads) may stay in flight (T4)
    if (it + 1 < nIter) { asm volatile("s_waitcnt vmcnt(8)" ::: "memory"); }
    else                { asm volatile("s_waitcnt vmcnt(0)" ::: "memory"); }
    __builtin_amdgcn_s_barrier();
    __builtin_amdgcn_sched_barrier(0);

    // ---- S^T = K Q^T : lane holds S[q=lr][key=kv0+n*16+lh*4+r] ----
    const char* kb = (const char*)&Ks[cur][0];
    f32x4 s0[4] = {}, s1[4] = {};
    __builtin_amdgcn_s_setprio(1);
    #pragma unroll
    for (int n = 0; n < 4; ++n) {
      const int row = n * 16 + lr;
      const int sw = (row & 7) << 4;
      #pragma unroll
      for (int kc = 0; kc < 4; ++kc) {
        bf16x8 kf = *reinterpret_cast<const bf16x8*>(kb + row * 256 + ((kc * 64 + lh * 16) ^ sw));
        s0[n] = __builtin_amdgcn_mfma_f32_16x16x32_bf16(kf, qf[0][kc], s0[n], 0, 0, 0);
        s1[n] = __builtin_amdgcn_mfma_f32_16x16x32_bf16(kf, qf[1][kc], s1[n], 0, 0, 0);
      }
    }
    __builtin_amdgcn_s_setprio(0);

    // ---- P = exp2(S) in registers, packed as PV A-fragments ----
    // k-map for PV MFMA kc2: elements 0-3 <- n=2*kc2 (keys +lh*4+r), 4-7 <- n=2*kc2+1
    bf16x8 pa[2][2];
    #pragma unroll
    for (int sub = 0; sub < 2; ++sub) {
      const int qs = q0w + sub * 16;
      const bool needM = (kv0 + 63 > qs);
      #pragma unroll
      for (int kc2 = 0; kc2 < 2; ++kc2) {
        bf16x8 v;
        #pragma unroll
        for (int half = 0; half < 2; ++half) {
          const int n = kc2 * 2 + half;
          f32x4 sv = sub ? s1[n] : s0[n];
          #pragma unroll
          for (int r = 0; r < 4; ++r) {
            float p = exp2f(sv[r]);
            if (needM && (kv0 + n * 16 + lh * 4 + r > qs + lr)) p = 0.f;
            lsum4[sub][r] += p;                      // 4 independent chains
            v[half * 4 + r] = (bf16_t)p;
          }
        }
        pa[sub][kc2] = v;
      }
    }

    // ---- O += P V : B-frag = V^T rows (d), two b64 reads per fragment ----
    const char* vb0 = (const char*)&Vs[cur][0];
    __builtin_amdgcn_s_setprio(1);
    #pragma unroll
    for (int kc2 = 0; kc2 < 2; ++kc2) {
      #pragma unroll
      for (int nb = 0; nb < 8; ++nb) {
        const int row = nb * 16 + lr;
        const int sw2 = (row & 7) << 4;
        const char* vb = vb0 + row * 128;
        bf16x4 lo = *reinterpret_cast<const bf16x4*>(vb + ((kc2 * 64 + lh * 8) ^ sw2));
        bf16x4 hi = *reinterpret_cast<const bf16x4*>(vb + ((kc2 * 64 + 32 + lh * 8) ^ sw2));
        bf16x8 vf = __builtin_shufflevector(lo, hi, 0, 1, 2, 3, 4, 5, 6, 7);
        oacc[0][nb] = __builtin_amdgcn_mfma_f32_16x16x32_bf16(pa[0][kc2], vf, oacc[0][nb], 0, 0, 0);
        oacc[1][nb] = __builtin_amdgcn_mfma_f32_16x16x32_bf16(pa[1][kc2], vf, oacc[1][nb], 0, 0, 0);
      }
    }
    __builtin_amdgcn_s_setprio(0);

    // ---- all waves done reading buf cur -> refill it for tile it+2 ----
    __builtin_amdgcn_sched_barrier(0);
    __builtin_amdgcn_s_barrier();
    __builtin_amdgcn_sched_barrier(0);
    if (it + 2 < nIter) { STAGE_K(cur, kv0 + 128); STAGE_V(cur, kv0 + 128); }
  }

  // ---- row sums: fold 4 partials, then lh groups ----
  #pragma unroll
  for (int sub = 0; sub < 2; ++sub) {
    float s = (lsum4[sub][0] + lsum4[sub][1]) + (lsum4[sub][2] + lsum4[sub][3]);
    s += __shfl_xor(s, 16);
    s += __shfl_xor(s, 32);     // lane now holds full sum for q = qs + lr
    f32x4 linv;
    #pragma unroll
    for (int r = 0; r < 4; ++r) linv[r] = 1.0f / __shfl(s, lh * 4 + r);
    #pragma unroll
    for (int nb = 0; nb < 8; ++nb) {
      #pragma unroll
      for (int r = 0; r < 4; ++r) {
        float v = oacc[sub][nb][r] * linv[r];
        Ob[(size_t)(q0w + sub * 16 + lh * 4 + r) * 2048 + h * 128 + nb * 16 + lr] = (bf16_t)v;
      }
    }
  }
#undef STAGE_K
#undef STAGE_V
}

extern "C" void kernel_launch(void* const* d_in, const int* in_sizes, int n_in,
                              void* d_out, int out_size, void* d_ws, size_t ws_size,
                              hipStream_t stream) {
  const float* seq   = (const float*)d_in[0];
  const float* Wq_w  = (const float*)d_in[2];
  const float* Wq_b  = (const float*)d_in[3];
  const float* Wkv_w = (const float*)d_in[4];
  const float* Wkv_b = (const float*)d_in[5];
  const float* Wo_w  = (const float*)d_in[6];
  const float* Wo_b  = (const float*)d_in[7];

  float* out   = (float*)d_out;
  float* kvout = out + (size_t)4096 * 2048;

  char* ws = (char*)d_ws;
  bf16_t* seqb = (bf16_t*)ws;                          // [4096][2048] (reused as Ob)
  bf16_t* wqkv = (bf16_t*)(ws + 16777216);             // [3072][2048]
  bf16_t* wob  = (bf16_t*)(ws + 29360128);             // [2048][2048]
  bf16_t* qkvb = (bf16_t*)(ws + 37748736);             // [4096][3072]
  bf16_t* vt   = (bf16_t*)(ws + 62914560);             // [4][128][4096]
  bf16_t* ob   = seqb;

  cast_kernel<<<4096, 256, 0, stream>>>(seq, seqb, 1048576);
  cast_kernel<<<2048, 256, 0, stream>>>(Wq_w, wqkv, 524288);
  cast_kernel<<<1024, 256, 0, stream>>>(Wkv_w, wqkv + 4194304, 262144);
  cast_kernel<<<2048, 256, 0, stream>>>(Wo_w, wob, 524288);

  gemm_bt<1><<<dim3(32, 24), 256, 0, stream>>>(seqb, wqkv, Wq_b, Wkv_b,
                                               qkvb, kvout, vt, 4096, 3072, 2048);
  attn_kernel<<<dim3(32, 16), 256, 0, stream>>>(qkvb, vt, ob);
  gemm_bt<0><<<dim3(32, 16), 256, 0, stream>>>(ob, wob, Wo_b, nullptr,
                                               out, nullptr, nullptr, 4096, 2048, 2048);
}

// Round 6
// 321.518 us; speedup vs baseline: 1.0909x; 1.0002x over previous
//
#include <hip/hip_runtime.h>
#include <cstdint>
#include <cstddef>

typedef __bf16 bf16_t;
typedef __bf16 bf16x4 __attribute__((ext_vector_type(4)));
typedef __bf16 bf16x8 __attribute__((ext_vector_type(8)));
typedef float  f32x4  __attribute__((ext_vector_type(4)));

#define LDQ 3072   // QKV buffer row stride (elements)

// ---------------- cast f32 -> bf16, 8 elems/thread ----------------
__global__ __launch_bounds__(256)
void cast_kernel(const float* __restrict__ in, bf16_t* __restrict__ out, int n8) {
  int i = blockIdx.x * 256 + threadIdx.x;
  if (i >= n8) return;
  const float4* p = reinterpret_cast<const float4*>(in) + (size_t)i * 2;
  float4 a = p[0], b = p[1];
  bf16x8 o;
  o[0] = (bf16_t)a.x; o[1] = (bf16_t)a.y; o[2] = (bf16_t)a.z; o[3] = (bf16_t)a.w;
  o[4] = (bf16_t)b.x; o[5] = (bf16_t)b.y; o[6] = (bf16_t)b.z; o[7] = (bf16_t)b.w;
  *reinterpret_cast<bf16x8*>(out + (size_t)i * 8) = o;
}

// ---------------- GEMM: C[M,N] = A[M,K] * B[N,K]^T + bias ----------------
// MODE 1 scales the Q section (cols<2048) by log2(e)/sqrt(128).
template <int MODE>
__global__ __launch_bounds__(256)
void gemm_bt(const bf16_t* __restrict__ A, const bf16_t* __restrict__ B,
             const float* __restrict__ bias0, const float* __restrict__ bias1,
             void* __restrict__ out0, float* __restrict__ kvout,
             bf16_t* __restrict__ vt, int M, int N, int K) {
  __shared__ __align__(16) bf16_t As[128][64];
  __shared__ __align__(16) bf16_t Bs[128][64];
  const int t = threadIdx.x;
  const int l = t & 63, w = t >> 6;
  const int lr = l & 15, lh = l >> 4;
  const int m0 = blockIdx.x * 128, n0 = blockIdx.y * 128;
  const int wm = (w >> 1) * 64, wn = (w & 1) * 64;

  f32x4 acc[4][4] = {};

  for (int kt = 0; kt < K; kt += 64) {
    #pragma unroll
    for (int it = 0; it < 4; ++it) {
      int e = (it * 256 + t) * 8;
      int row = e >> 6, col = e & 63;
      __builtin_amdgcn_global_load_lds(
          (const __attribute__((address_space(1))) void*)(A + (size_t)(m0 + row) * K + kt + col),
          (__attribute__((address_space(3))) void*)(&As[row][col]), 16, 0, 0);
      __builtin_amdgcn_global_load_lds(
          (const __attribute__((address_space(1))) void*)(B + (size_t)(n0 + row) * K + kt + col),
          (__attribute__((address_space(3))) void*)(&Bs[row][col]), 16, 0, 0);
    }
    __syncthreads();
    #pragma unroll
    for (int ks = 0; ks < 2; ++ks) {
      bf16x8 a[4], b[4];
      #pragma unroll
      for (int i = 0; i < 4; ++i)
        a[i] = *reinterpret_cast<const bf16x8*>(&As[wm + i * 16 + lr][ks * 32 + lh * 8]);
      #pragma unroll
      for (int j = 0; j < 4; ++j)
        b[j] = *reinterpret_cast<const bf16x8*>(&Bs[wn + j * 16 + lr][ks * 32 + lh * 8]);
      #pragma unroll
      for (int i = 0; i < 4; ++i)
        #pragma unroll
        for (int j = 0; j < 4; ++j)
          acc[i][j] = __builtin_amdgcn_mfma_f32_16x16x32_bf16(a[i], b[j], acc[i][j], 0, 0, 0);
    }
    __syncthreads();
  }

  #pragma unroll
  for (int j = 0; j < 4; ++j) {
    const int col = n0 + wn + j * 16 + lr;
    float bv;
    if constexpr (MODE == 0) bv = bias0[col];
    else bv = (col < 2048) ? bias0[col] : bias1[col - 2048];
    #pragma unroll
    for (int i = 0; i < 4; ++i) {
      #pragma unroll
      for (int r = 0; r < 4; ++r) {
        const int row = m0 + wm + i * 16 + lh * 4 + r;
        float v = acc[i][j][r] + bv;
        if constexpr (MODE == 0) {
          reinterpret_cast<float*>(out0)[(size_t)row * N + col] = v;
        } else {
          float qv = (col < 2048) ? v * 0.1275187541f : v;
          reinterpret_cast<bf16_t*>(out0)[(size_t)row * N + col] = (bf16_t)qv;
          if (col >= 2048) {
            const int local = col - 2048;
            const int which = local >> 9;
            const int hd    = local & 511;
            kvout[(size_t)which * 2097152 +
                  ((size_t)(hd >> 7) * 4096 + row) * 128 + (hd & 127)] = v;
            if (local >= 512) {
              const int c2 = local - 512;
              vt[(size_t)(c2 >> 7) * 524288 + (size_t)(c2 & 127) * 4096 + row] = (bf16_t)v;
            }
          }
        }
      }
    }
  }
}

// ---------------- causal GQA flash attention ----------------
// grid (16, 16) = 256 blocks, 1 per CU. Each block serially processes the
// complementary q-tile pair {x, 31-x}: every block = exactly 66 KV-tile iters
// -> perfect load balance independent of dispatch placement.
// 4 waves x 32 q-rows (2 subtiles), KV tile 64, K+V double-buffered, in-reg P.
__global__ __launch_bounds__(256, 2)
void attn_kernel(const bf16_t* __restrict__ QKVb, const bf16_t* __restrict__ Vt,
                 bf16_t* __restrict__ Ob) {
  __shared__ __align__(16) bf16_t Ks[2][64 * 128];   // swizzled K tiles (256B rows)
  __shared__ __align__(16) bf16_t Vs[2][128 * 64];   // swizzled V^T tiles (128B rows)
  const int t = threadIdx.x;
  const int w = t >> 6, l = t & 63;
  const int lr = l & 15, lh = l >> 4;
  const int h = blockIdx.y, kvh = h >> 2;

  const char* Kg = (const char*)(QKVb + 2048 + (size_t)kvh * 128);  // row 6144 B
  const char* Vg = (const char*)(Vt + (size_t)kvh * 524288);        // row 8192 B

#define STAGE_K(buf, kv0)                                                          \
  {                                                                                \
    _Pragma("unroll")                                                              \
    for (int p = 0; p < 4; ++p) {                                                  \
      int chunk = p * 256 + t;                                                     \
      int row = chunk >> 4, cb = (chunk & 15) << 4;                                \
      __builtin_amdgcn_global_load_lds(                                            \
        (const __attribute__((address_space(1))) void*)                            \
            (Kg + (size_t)((kv0) + row) * 6144 + (cb ^ ((row & 7) << 4))),         \
        (__attribute__((address_space(3))) void*)((char*)&Ks[buf][0] + chunk * 16),\
        16, 0, 0);                                                                 \
    }                                                                              \
  }
#define STAGE_V(buf, kv0)                                                          \
  {                                                                                \
    _Pragma("unroll")                                                              \
    for (int p = 0; p < 4; ++p) {                                                  \
      int chunk = p * 256 + t;                                                     \
      int row = chunk >> 3, cb = (chunk & 7) << 4;                                 \
      __builtin_amdgcn_global_load_lds(                                            \
        (const __attribute__((address_space(1))) void*)                            \
            (Vg + (size_t)row * 8192 + (size_t)(kv0) * 2 + (cb ^ ((row & 7) << 4))),\
        (__attribute__((address_space(3))) void*)((char*)&Vs[buf][0] + chunk * 16),\
        16, 0, 0);                                                                 \
    }                                                                              \
  }

  bf16x8 onesf;
  #pragma unroll
  for (int j = 0; j < 8; ++j) onesf[j] = (bf16_t)1.0f;

  for (int ph = 0; ph < 2; ++ph) {
    const int xt = ph ? 31 - (int)blockIdx.x : (int)blockIdx.x;   // pair {x, 31-x}
    const int q0w = xt * 128 + w * 32;
    const int nIter = 2 * xt + 2;

    // Q fragments for this phase
    bf16x8 qf[2][4];
    #pragma unroll
    for (int sub = 0; sub < 2; ++sub) {
      const bf16_t* qp = QKVb + (size_t)(q0w + sub * 16 + lr) * LDQ + h * 128 + lh * 8;
      #pragma unroll
      for (int kc = 0; kc < 4; ++kc) qf[sub][kc] = *reinterpret_cast<const bf16x8*>(qp + kc * 32);
    }

    STAGE_K(0, 0);
    STAGE_V(0, 0);
    STAGE_K(1, 64);     // nIter >= 2 always
    STAGE_V(1, 64);

    f32x4 oacc[2][8] = {};
    f32x4 lacc[2] = {};

    // one KV-tile step; `masked` is compile-time at each call site
    auto body = [&](int it, bool masked) {
      const int cur = it & 1;
      const int kv0 = it * 64;
      if (it + 1 < nIter) { asm volatile("s_waitcnt vmcnt(8)" ::: "memory"); }
      else                { asm volatile("s_waitcnt vmcnt(0)" ::: "memory"); }
      __builtin_amdgcn_s_barrier();
      __builtin_amdgcn_sched_barrier(0);

      // ---- S^T = K Q^T : lane holds S[q=lr][key=kv0+n*16+lh*4+r] ----
      const char* kb = (const char*)&Ks[cur][0];
      f32x4 s0[4] = {}, s1[4] = {};
      __builtin_amdgcn_s_setprio(1);
      #pragma unroll
      for (int n = 0; n < 4; ++n) {
        const int row = n * 16 + lr;
        const int sw = (row & 7) << 4;
        #pragma unroll
        for (int kc = 0; kc < 4; ++kc) {
          bf16x8 kf = *reinterpret_cast<const bf16x8*>(kb + row * 256 + ((kc * 64 + lh * 16) ^ sw));
          s0[n] = __builtin_amdgcn_mfma_f32_16x16x32_bf16(kf, qf[0][kc], s0[n], 0, 0, 0);
          s1[n] = __builtin_amdgcn_mfma_f32_16x16x32_bf16(kf, qf[1][kc], s1[n], 0, 0, 0);
        }
      }
      __builtin_amdgcn_s_setprio(0);

      // ---- P = exp2(S) in registers, packed as PV A-fragments ----
      bf16x8 pa[2][2];
      #pragma unroll
      for (int sub = 0; sub < 2; ++sub) {
        const int qs = q0w + sub * 16;
        const bool needM = masked && (kv0 + 63 > qs);
        #pragma unroll
        for (int kc2 = 0; kc2 < 2; ++kc2) {
          bf16x8 v;
          #pragma unroll
          for (int half = 0; half < 2; ++half) {
            const int n = kc2 * 2 + half;
            f32x4 sv = sub ? s1[n] : s0[n];
            #pragma unroll
            for (int r = 0; r < 4; ++r) {
              float p = exp2f(sv[r]);
              if (needM && (kv0 + n * 16 + lh * 4 + r > qs + lr)) p = 0.f;
              v[half * 4 + r] = (bf16_t)p;
            }
          }
          pa[sub][kc2] = v;
        }
      }
      // row sums via ones-MFMA: lacc[sub][r] = rowsum(P)[q_row = lh*4+r] (exact, no shuffles)
      lacc[0] = __builtin_amdgcn_mfma_f32_16x16x32_bf16(pa[0][0], onesf, lacc[0], 0, 0, 0);
      lacc[0] = __builtin_amdgcn_mfma_f32_16x16x32_bf16(pa[0][1], onesf, lacc[0], 0, 0, 0);
      lacc[1] = __builtin_amdgcn_mfma_f32_16x16x32_bf16(pa[1][0], onesf, lacc[1], 0, 0, 0);
      lacc[1] = __builtin_amdgcn_mfma_f32_16x16x32_bf16(pa[1][1], onesf, lacc[1], 0, 0, 0);

      // ---- gate V(it): next tile's 8 loads may stay in flight (T4) ----
      asm volatile("s_waitcnt vmcnt(8)" ::: "memory");
      __builtin_amdgcn_s_barrier();
      __builtin_amdgcn_sched_barrier(0);

      // ---- O += P V : B-frag = V^T rows (d), two b64 reads per fragment ----
      const char* vb0 = (const char*)&Vs[cur][0];
      __builtin_amdgcn_s_setprio(1);
      #pragma unroll
      for (int kc2 = 0; kc2 < 2; ++kc2) {
        #pragma unroll
        for (int nb = 0; nb < 8; ++nb) {
          const int row = nb * 16 + lr;
          const int sw2 = (row & 7) << 4;
          const char* vb = vb0 + row * 128;
          bf16x4 lo = *reinterpret_cast<const bf16x4*>(vb + ((kc2 * 64 + lh * 8) ^ sw2));
          bf16x4 hi = *reinterpret_cast<const bf16x4*>(vb + ((kc2 * 64 + 32 + lh * 8) ^ sw2));
          bf16x8 vf = __builtin_shufflevector(lo, hi, 0, 1, 2, 3, 4, 5, 6, 7);
          oacc[0][nb] = __builtin_amdgcn_mfma_f32_16x16x32_bf16(pa[0][kc2], vf, oacc[0][nb], 0, 0, 0);
          oacc[1][nb] = __builtin_amdgcn_mfma_f32_16x16x32_bf16(pa[1][kc2], vf, oacc[1][nb], 0, 0, 0);
        }
      }
      __builtin_amdgcn_s_setprio(0);

      // ---- all waves done reading buf cur -> refill it for tile it+2 ----
      __builtin_amdgcn_sched_barrier(0);
      __builtin_amdgcn_s_barrier();
      __builtin_amdgcn_sched_barrier(0);
      if (it + 2 < nIter) { STAGE_K(cur, kv0 + 128); STAGE_V(cur, kv0 + 128); }
    };

    for (int it = 0; it < nIter - 2; ++it) body(it, false);   // unmasked main loop
    body(nIter - 2, true);                                    // diagonal-spanning
    body(nIter - 1, true);

    // ---- epilogue: normalize and store ----
    #pragma unroll
    for (int sub = 0; sub < 2; ++sub) {
      f32x4 linv;
      #pragma unroll
      for (int r = 0; r < 4; ++r) linv[r] = 1.0f / lacc[sub][r];
      #pragma unroll
      for (int nb = 0; nb < 8; ++nb) {
        #pragma unroll
        for (int r = 0; r < 4; ++r) {
          float v = oacc[sub][nb][r] * linv[r];
          Ob[(size_t)(q0w + sub * 16 + lh * 4 + r) * 2048 + h * 128 + nb * 16 + lr] = (bf16_t)v;
        }
      }
    }
  }
#undef STAGE_K
#undef STAGE_V
}

extern "C" void kernel_launch(void* const* d_in, const int* in_sizes, int n_in,
                              void* d_out, int out_size, void* d_ws, size_t ws_size,
                              hipStream_t stream) {
  const float* seq   = (const float*)d_in[0];
  const float* Wq_w  = (const float*)d_in[2];
  const float* Wq_b  = (const float*)d_in[3];
  const float* Wkv_w = (const float*)d_in[4];
  const float* Wkv_b = (const float*)d_in[5];
  const float* Wo_w  = (const float*)d_in[6];
  const float* Wo_b  = (const float*)d_in[7];

  float* out   = (float*)d_out;
  float* kvout = out + (size_t)4096 * 2048;

  char* ws = (char*)d_ws;
  bf16_t* seqb = (bf16_t*)ws;                          // [4096][2048] (reused as Ob)
  bf16_t* wqkv = (bf16_t*)(ws + 16777216);             // [3072][2048]
  bf16_t* wob  = (bf16_t*)(ws + 29360128);             // [2048][2048]
  bf16_t* qkvb = (bf16_t*)(ws + 37748736);             // [4096][3072]
  bf16_t* vt   = (bf16_t*)(ws + 62914560);             // [4][128][4096]
  bf16_t* ob   = seqb;

  cast_kernel<<<4096, 256, 0, stream>>>(seq, seqb, 1048576);
  cast_kernel<<<2048, 256, 0, stream>>>(Wq_w, wqkv, 524288);
  cast_kernel<<<1024, 256, 0, stream>>>(Wkv_w, wqkv + 4194304, 262144);
  cast_kernel<<<2048, 256, 0, stream>>>(Wo_w, wob, 524288);

  gemm_bt<1><<<dim3(32, 24), 256, 0, stream>>>(seqb, wqkv, Wq_b, Wkv_b,
                                               qkvb, kvout, vt, 4096, 3072, 2048);
  attn_kernel<<<dim3(16, 16), 256, 0, stream>>>(qkvb, vt, ob);
  gemm_bt<0><<<dim3(32, 16), 256, 0, stream>>>(ob, wob, Wo_b, nullptr,
                                               out, nullptr, nullptr, 4096, 2048, 2048);
}

// Round 7
// 313.024 us; speedup vs baseline: 1.1205x; 1.0271x over previous
//
#include <hip/hip_runtime.h>
#include <cstdint>
#include <cstddef>

typedef __bf16 bf16_t;
typedef __bf16 bf16x4 __attribute__((ext_vector_type(4)));
typedef __bf16 bf16x8 __attribute__((ext_vector_type(8)));
typedef float  f32x4  __attribute__((ext_vector_type(4)));

#define LDQ 3072   // QKV buffer row stride (elements)

// ---------------- cast f32 -> bf16, 8 elems/thread ----------------
__global__ __launch_bounds__(256)
void cast_kernel(const float* __restrict__ in, bf16_t* __restrict__ out, int n8) {
  int i = blockIdx.x * 256 + threadIdx.x;
  if (i >= n8) return;
  const float4* p = reinterpret_cast<const float4*>(in) + (size_t)i * 2;
  float4 a = p[0], b = p[1];
  bf16x8 o;
  o[0] = (bf16_t)a.x; o[1] = (bf16_t)a.y; o[2] = (bf16_t)a.z; o[3] = (bf16_t)a.w;
  o[4] = (bf16_t)b.x; o[5] = (bf16_t)b.y; o[6] = (bf16_t)b.z; o[7] = (bf16_t)b.w;
  *reinterpret_cast<bf16x8*>(out + (size_t)i * 8) = o;
}

// ---------------- GEMM: C[M,N] = A[M,K] * B[N,K]^T + bias ----------------
// MODE 1 scales the Q section (cols<2048) by log2(e)/sqrt(128).
template <int MODE>
__global__ __launch_bounds__(256)
void gemm_bt(const bf16_t* __restrict__ A, const bf16_t* __restrict__ B,
             const float* __restrict__ bias0, const float* __restrict__ bias1,
             void* __restrict__ out0, float* __restrict__ kvout,
             bf16_t* __restrict__ vt, int M, int N, int K) {
  __shared__ __align__(16) bf16_t As[128][64];
  __shared__ __align__(16) bf16_t Bs[128][64];
  const int t = threadIdx.x;
  const int l = t & 63, w = t >> 6;
  const int lr = l & 15, lh = l >> 4;
  const int m0 = blockIdx.x * 128, n0 = blockIdx.y * 128;
  const int wm = (w >> 1) * 64, wn = (w & 1) * 64;

  f32x4 acc[4][4] = {};

  for (int kt = 0; kt < K; kt += 64) {
    #pragma unroll
    for (int it = 0; it < 4; ++it) {
      int e = (it * 256 + t) * 8;
      int row = e >> 6, col = e & 63;
      __builtin_amdgcn_global_load_lds(
          (const __attribute__((address_space(1))) void*)(A + (size_t)(m0 + row) * K + kt + col),
          (__attribute__((address_space(3))) void*)(&As[row][col]), 16, 0, 0);
      __builtin_amdgcn_global_load_lds(
          (const __attribute__((address_space(1))) void*)(B + (size_t)(n0 + row) * K + kt + col),
          (__attribute__((address_space(3))) void*)(&Bs[row][col]), 16, 0, 0);
    }
    __syncthreads();
    #pragma unroll
    for (int ks = 0; ks < 2; ++ks) {
      bf16x8 a[4], b[4];
      #pragma unroll
      for (int i = 0; i < 4; ++i)
        a[i] = *reinterpret_cast<const bf16x8*>(&As[wm + i * 16 + lr][ks * 32 + lh * 8]);
      #pragma unroll
      for (int j = 0; j < 4; ++j)
        b[j] = *reinterpret_cast<const bf16x8*>(&Bs[wn + j * 16 + lr][ks * 32 + lh * 8]);
      #pragma unroll
      for (int i = 0; i < 4; ++i)
        #pragma unroll
        for (int j = 0; j < 4; ++j)
          acc[i][j] = __builtin_amdgcn_mfma_f32_16x16x32_bf16(a[i], b[j], acc[i][j], 0, 0, 0);
    }
    __syncthreads();
  }

  #pragma unroll
  for (int j = 0; j < 4; ++j) {
    const int col = n0 + wn + j * 16 + lr;
    float bv;
    if constexpr (MODE == 0) bv = bias0[col];
    else bv = (col < 2048) ? bias0[col] : bias1[col - 2048];
    #pragma unroll
    for (int i = 0; i < 4; ++i) {
      #pragma unroll
      for (int r = 0; r < 4; ++r) {
        const int row = m0 + wm + i * 16 + lh * 4 + r;
        float v = acc[i][j][r] + bv;
        if constexpr (MODE == 0) {
          reinterpret_cast<float*>(out0)[(size_t)row * N + col] = v;
        } else {
          float qv = (col < 2048) ? v * 0.1275187541f : v;
          reinterpret_cast<bf16_t*>(out0)[(size_t)row * N + col] = (bf16_t)qv;
          if (col >= 2048) {
            const int local = col - 2048;
            const int which = local >> 9;
            const int hd    = local & 511;
            kvout[(size_t)which * 2097152 +
                  ((size_t)(hd >> 7) * 4096 + row) * 128 + (hd & 127)] = v;
            if (local >= 512) {
              const int c2 = local - 512;
              vt[(size_t)(c2 >> 7) * 524288 + (size_t)(c2 & 127) * 4096 + row] = (bf16_t)v;
            }
          }
        }
      }
    }
  }
}

// ---------------- causal GQA flash attention ----------------
// grid (16, 16) = 256 blocks, 1 per CU, 512 threads = 8 waves (2/SIMD for TLP).
// Each block serially processes the complementary 128-row q-tile pair {x, 31-x}
// (exactly 66 KV-tile iters per block -> placement-independent balance).
// Each wave owns 16 q-rows. KV tile 64, K+V double-buffered, in-register P.
__global__ __launch_bounds__(512, 2)
void attn_kernel(const bf16_t* __restrict__ QKVb, const bf16_t* __restrict__ Vt,
                 bf16_t* __restrict__ Ob) {
  __shared__ __align__(16) bf16_t Ks[2][64 * 128];   // swizzled K tiles (256B rows)
  __shared__ __align__(16) bf16_t Vs[2][128 * 64];   // swizzled V^T tiles (128B rows)
  const int t = threadIdx.x;
  const int w = t >> 6, l = t & 63;
  const int lr = l & 15, lh = l >> 4;
  const int h = blockIdx.y, kvh = h >> 2;

  const char* Kg = (const char*)(QKVb + 2048 + (size_t)kvh * 128);  // row 6144 B
  const char* Vg = (const char*)(Vt + (size_t)kvh * 524288);        // row 8192 B

// 512 threads: 2 chunks of 16B per thread per tile
#define STAGE_K(buf, kv0)                                                          \
  {                                                                                \
    _Pragma("unroll")                                                              \
    for (int p = 0; p < 2; ++p) {                                                  \
      int chunk = p * 512 + t;                                                     \
      int row = chunk >> 4, cb = (chunk & 15) << 4;                                \
      __builtin_amdgcn_global_load_lds(                                            \
        (const __attribute__((address_space(1))) void*)                            \
            (Kg + (size_t)((kv0) + row) * 6144 + (cb ^ ((row & 7) << 4))),         \
        (__attribute__((address_space(3))) void*)((char*)&Ks[buf][0] + chunk * 16),\
        16, 0, 0);                                                                 \
    }                                                                              \
  }
#define STAGE_V(buf, kv0)                                                          \
  {                                                                                \
    _Pragma("unroll")                                                              \
    for (int p = 0; p < 2; ++p) {                                                  \
      int chunk = p * 512 + t;                                                     \
      int row = chunk >> 3, cb = (chunk & 7) << 4;                                 \
      __builtin_amdgcn_global_load_lds(                                            \
        (const __attribute__((address_space(1))) void*)                            \
            (Vg + (size_t)row * 8192 + (size_t)(kv0) * 2 + (cb ^ ((row & 7) << 4))),\
        (__attribute__((address_space(3))) void*)((char*)&Vs[buf][0] + chunk * 16),\
        16, 0, 0);                                                                 \
    }                                                                              \
  }

  bf16x8 onesf;
  #pragma unroll
  for (int j = 0; j < 8; ++j) onesf[j] = (bf16_t)1.0f;

  for (int ph = 0; ph < 2; ++ph) {
    const int xt = ph ? 31 - (int)blockIdx.x : (int)blockIdx.x;   // pair {x, 31-x}
    const int q0b = xt * 128;
    const int q0w = q0b + w * 16;          // this wave's 16 q-rows
    const int nIter = 2 * xt + 2;

    // Q fragments: lane holds Q[q0w+lr][kc*32 + lh*8 .. +7]
    bf16x8 qf[4];
    {
      const bf16_t* qp = QKVb + (size_t)(q0w + lr) * LDQ + h * 128 + lh * 8;
      #pragma unroll
      for (int kc = 0; kc < 4; ++kc) qf[kc] = *reinterpret_cast<const bf16x8*>(qp + kc * 32);
    }
    __builtin_amdgcn_sched_barrier(0);
    STAGE_K(0, 0);
    STAGE_V(0, 0);
    __builtin_amdgcn_sched_barrier(0);
    STAGE_K(1, 64);     // nIter >= 2 always
    STAGE_V(1, 64);
    __builtin_amdgcn_sched_barrier(0);

    f32x4 oacc[8] = {};
    f32x4 lacc = {};

    // one KV-tile step; `masked` is compile-time at each call site
    auto body = [&](int it, bool masked) {
      const int cur = it & 1;
      const int kv0 = it * 64;
      // tile it resident; tile it+1 (4 loads/thread) may stay in flight (T4)
      if (it + 1 < nIter) { asm volatile("s_waitcnt vmcnt(4)" ::: "memory"); }
      else                { asm volatile("s_waitcnt vmcnt(0)" ::: "memory"); }
      __builtin_amdgcn_s_barrier();
      __builtin_amdgcn_sched_barrier(0);

      // ---- S^T = K Q^T : lane holds S[q=lr][key=kv0+n*16+lh*4+r] ----
      const char* kb = (const char*)&Ks[cur][0];
      f32x4 s[4] = {};
      __builtin_amdgcn_s_setprio(1);
      #pragma unroll
      for (int n = 0; n < 4; ++n) {
        const int row = n * 16 + lr;
        const int sw = (row & 7) << 4;
        #pragma unroll
        for (int kc = 0; kc < 4; ++kc) {
          bf16x8 kf = *reinterpret_cast<const bf16x8*>(kb + row * 256 + ((kc * 64 + lh * 16) ^ sw));
          s[n] = __builtin_amdgcn_mfma_f32_16x16x32_bf16(kf, qf[kc], s[n], 0, 0, 0);
        }
      }
      __builtin_amdgcn_s_setprio(0);

      // ---- P = exp2(S) in registers, packed as PV A-fragments ----
      // k-map for PV MFMA kc2: elems 0-3 <- n=2*kc2 (keys +lh*4+r), 4-7 <- n=2*kc2+1
      bf16x8 pa[2];
      const bool needM = masked && (kv0 + 63 > q0w);
      #pragma unroll
      for (int kc2 = 0; kc2 < 2; ++kc2) {
        bf16x8 v;
        #pragma unroll
        for (int half = 0; half < 2; ++half) {
          const int n = kc2 * 2 + half;
          #pragma unroll
          for (int r = 0; r < 4; ++r) {
            float p = exp2f(s[n][r]);
            if (needM && (kv0 + n * 16 + lh * 4 + r > q0w + lr)) p = 0.f;
            v[half * 4 + r] = (bf16_t)p;
          }
        }
        pa[kc2] = v;
      }
      // row sums via ones-MFMA: lacc[r] = rowsum(P)[q = lh*4+r] (exact, no shuffles)
      lacc = __builtin_amdgcn_mfma_f32_16x16x32_bf16(pa[0], onesf, lacc, 0, 0, 0);
      lacc = __builtin_amdgcn_mfma_f32_16x16x32_bf16(pa[1], onesf, lacc, 0, 0, 0);

      // ---- O += P V : B-frag = V^T rows (d), two b64 reads per fragment ----
      const char* vb0 = (const char*)&Vs[cur][0];
      __builtin_amdgcn_s_setprio(1);
      #pragma unroll
      for (int kc2 = 0; kc2 < 2; ++kc2) {
        #pragma unroll
        for (int nb = 0; nb < 8; ++nb) {
          const int row = nb * 16 + lr;
          const int sw2 = (row & 7) << 4;
          const char* vb = vb0 + row * 128;
          bf16x4 lo = *reinterpret_cast<const bf16x4*>(vb + ((kc2 * 64 + lh * 8) ^ sw2));
          bf16x4 hi = *reinterpret_cast<const bf16x4*>(vb + ((kc2 * 64 + 32 + lh * 8) ^ sw2));
          bf16x8 vf = __builtin_shufflevector(lo, hi, 0, 1, 2, 3, 4, 5, 6, 7);
          oacc[nb] = __builtin_amdgcn_mfma_f32_16x16x32_bf16(pa[kc2], vf, oacc[nb], 0, 0, 0);
        }
      }
      __builtin_amdgcn_s_setprio(0);

      // ---- all waves done reading buf cur -> refill it for tile it+2 ----
      __builtin_amdgcn_sched_barrier(0);
      __builtin_amdgcn_s_barrier();
      __builtin_amdgcn_sched_barrier(0);
      if (it + 2 < nIter) { STAGE_K(cur, kv0 + 128); STAGE_V(cur, kv0 + 128); }
    };

    for (int it = 0; it < nIter - 2; ++it) body(it, false);   // unmasked main loop
    body(nIter - 2, true);                                    // diagonal band
    body(nIter - 1, true);

    // ---- epilogue: normalize and store ----
    f32x4 linv;
    #pragma unroll
    for (int r = 0; r < 4; ++r) linv[r] = 1.0f / lacc[r];
    #pragma unroll
    for (int nb = 0; nb < 8; ++nb) {
      #pragma unroll
      for (int r = 0; r < 4; ++r) {
        float v = oacc[nb][r] * linv[r];
        Ob[(size_t)(q0w + lh * 4 + r) * 2048 + h * 128 + nb * 16 + lr] = (bf16_t)v;
      }
    }
  }
#undef STAGE_K
#undef STAGE_V
}

extern "C" void kernel_launch(void* const* d_in, const int* in_sizes, int n_in,
                              void* d_out, int out_size, void* d_ws, size_t ws_size,
                              hipStream_t stream) {
  const float* seq   = (const float*)d_in[0];
  const float* Wq_w  = (const float*)d_in[2];
  const float* Wq_b  = (const float*)d_in[3];
  const float* Wkv_w = (const float*)d_in[4];
  const float* Wkv_b = (const float*)d_in[5];
  const float* Wo_w  = (const float*)d_in[6];
  const float* Wo_b  = (const float*)d_in[7];

  float* out   = (float*)d_out;
  float* kvout = out + (size_t)4096 * 2048;

  char* ws = (char*)d_ws;
  bf16_t* seqb = (bf16_t*)ws;                          // [4096][2048] (reused as Ob)
  bf16_t* wqkv = (bf16_t*)(ws + 16777216);             // [3072][2048]
  bf16_t* wob  = (bf16_t*)(ws + 29360128);             // [2048][2048]
  bf16_t* qkvb = (bf16_t*)(ws + 37748736);             // [4096][3072]
  bf16_t* vt   = (bf16_t*)(ws + 62914560);             // [4][128][4096]
  bf16_t* ob   = seqb;

  cast_kernel<<<4096, 256, 0, stream>>>(seq, seqb, 1048576);
  cast_kernel<<<2048, 256, 0, stream>>>(Wq_w, wqkv, 524288);
  cast_kernel<<<1024, 256, 0, stream>>>(Wkv_w, wqkv + 4194304, 262144);
  cast_kernel<<<2048, 256, 0, stream>>>(Wo_w, wob, 524288);

  gemm_bt<1><<<dim3(32, 24), 256, 0, stream>>>(seqb, wqkv, Wq_b, Wkv_b,
                                               qkvb, kvout, vt, 4096, 3072, 2048);
  attn_kernel<<<dim3(16, 16), 512, 0, stream>>>(qkvb, vt, ob);
  gemm_bt<0><<<dim3(32, 16), 256, 0, stream>>>(ob, wob, Wo_b, nullptr,
                                               out, nullptr, nullptr, 4096, 2048, 2048);
}

// Round 8
// 274.883 us; speedup vs baseline: 1.2759x; 1.1388x over previous
//
#include <hip/hip_runtime.h>
#include <cstdint>
#include <cstddef>

typedef __bf16 bf16_t;
typedef __bf16 bf16x4 __attribute__((ext_vector_type(4)));
typedef __bf16 bf16x8 __attribute__((ext_vector_type(8)));
typedef float  f32x4  __attribute__((ext_vector_type(4)));

#define LDQ 3072   // QKV buffer row stride (elements)

// ---------------- cast f32 -> bf16, 8 elems/thread ----------------
__global__ __launch_bounds__(256)
void cast_kernel(const float* __restrict__ in, bf16_t* __restrict__ out, int n8) {
  int i = blockIdx.x * 256 + threadIdx.x;
  if (i >= n8) return;
  const float4* p = reinterpret_cast<const float4*>(in) + (size_t)i * 2;
  float4 a = p[0], b = p[1];
  bf16x8 o;
  o[0] = (bf16_t)a.x; o[1] = (bf16_t)a.y; o[2] = (bf16_t)a.z; o[3] = (bf16_t)a.w;
  o[4] = (bf16_t)b.x; o[5] = (bf16_t)b.y; o[6] = (bf16_t)b.z; o[7] = (bf16_t)b.w;
  *reinterpret_cast<bf16x8*>(out + (size_t)i * 8) = o;
}

// ---------------- GEMM: C[M,N] = A[M,K] * B[N,K]^T + bias ----------------
// MODE 1 scales the Q section (cols<2048) by log2(e)/sqrt(128).
template <int MODE>
__global__ __launch_bounds__(256)
void gemm_bt(const bf16_t* __restrict__ A, const bf16_t* __restrict__ B,
             const float* __restrict__ bias0, const float* __restrict__ bias1,
             void* __restrict__ out0, float* __restrict__ kvout,
             bf16_t* __restrict__ vt, int M, int N, int K) {
  __shared__ __align__(16) bf16_t As[128][64];
  __shared__ __align__(16) bf16_t Bs[128][64];
  const int t = threadIdx.x;
  const int l = t & 63, w = t >> 6;
  const int lr = l & 15, lh = l >> 4;
  const int m0 = blockIdx.x * 128, n0 = blockIdx.y * 128;
  const int wm = (w >> 1) * 64, wn = (w & 1) * 64;

  f32x4 acc[4][4] = {};

  for (int kt = 0; kt < K; kt += 64) {
    #pragma unroll
    for (int it = 0; it < 4; ++it) {
      int e = (it * 256 + t) * 8;
      int row = e >> 6, col = e & 63;
      __builtin_amdgcn_global_load_lds(
          (const __attribute__((address_space(1))) void*)(A + (size_t)(m0 + row) * K + kt + col),
          (__attribute__((address_space(3))) void*)(&As[row][col]), 16, 0, 0);
      __builtin_amdgcn_global_load_lds(
          (const __attribute__((address_space(1))) void*)(B + (size_t)(n0 + row) * K + kt + col),
          (__attribute__((address_space(3))) void*)(&Bs[row][col]), 16, 0, 0);
    }
    __syncthreads();
    #pragma unroll
    for (int ks = 0; ks < 2; ++ks) {
      bf16x8 a[4], b[4];
      #pragma unroll
      for (int i = 0; i < 4; ++i)
        a[i] = *reinterpret_cast<const bf16x8*>(&As[wm + i * 16 + lr][ks * 32 + lh * 8]);
      #pragma unroll
      for (int j = 0; j < 4; ++j)
        b[j] = *reinterpret_cast<const bf16x8*>(&Bs[wn + j * 16 + lr][ks * 32 + lh * 8]);
      #pragma unroll
      for (int i = 0; i < 4; ++i)
        #pragma unroll
        for (int j = 0; j < 4; ++j)
          acc[i][j] = __builtin_amdgcn_mfma_f32_16x16x32_bf16(a[i], b[j], acc[i][j], 0, 0, 0);
    }
    __syncthreads();
  }

  #pragma unroll
  for (int j = 0; j < 4; ++j) {
    const int col = n0 + wn + j * 16 + lr;
    float bv;
    if constexpr (MODE == 0) bv = bias0[col];
    else bv = (col < 2048) ? bias0[col] : bias1[col - 2048];
    #pragma unroll
    for (int i = 0; i < 4; ++i) {
      #pragma unroll
      for (int r = 0; r < 4; ++r) {
        const int row = m0 + wm + i * 16 + lh * 4 + r;
        float v = acc[i][j][r] + bv;
        if constexpr (MODE == 0) {
          reinterpret_cast<float*>(out0)[(size_t)row * N + col] = v;
        } else {
          float qv = (col < 2048) ? v * 0.1275187541f : v;
          reinterpret_cast<bf16_t*>(out0)[(size_t)row * N + col] = (bf16_t)qv;
          if (col >= 2048) {
            const int local = col - 2048;
            const int which = local >> 9;
            const int hd    = local & 511;
            kvout[(size_t)which * 2097152 +
                  ((size_t)(hd >> 7) * 4096 + row) * 128 + (hd & 127)] = v;
            if (local >= 512) {
              const int c2 = local - 512;
              vt[(size_t)(c2 >> 7) * 524288 + (size_t)(c2 & 127) * 4096 + row] = (bf16_t)v;
            }
          }
        }
      }
    }
  }
}

// ---------------- causal GQA flash attention ----------------
// grid (16, 16), 512 threads = 8 waves. Block processes the complementary
// 128-row q-tile pair {x, 31-x} (66 KV-iters per block, placement-independent).
// Wave-group split over KEYS: waves 0-3 = keys [0,32) of each tile, waves 4-7
// = keys [32,64); each wave covers 32 q-rows (2 subtiles). Fixed-max softmax
// makes key-split exact (pure sums); partials merged through LDS per phase.
__global__ __launch_bounds__(512, 2)
void attn_kernel(const bf16_t* __restrict__ QKVb, const bf16_t* __restrict__ Vt,
                 bf16_t* __restrict__ Ob) {
  __shared__ __align__(16) char smem[65536];   // [0,32K): K tiles x2 ; [32K,64K): V tiles x2
  const int t = threadIdx.x;
  const int w = t >> 6, l = t & 63;
  const int lr = l & 15, lh = l >> 4;
  const int g = w >> 2;                        // key-half group
  const int wq = w & 3;                        // q-subtile owner (32 rows)
  const int h = blockIdx.y, kvh = h >> 2;

  const char* Kg = (const char*)(QKVb + 2048 + (size_t)kvh * 128);  // row 6144 B
  const char* Vg = (const char*)(Vt + (size_t)kvh * 524288);        // row 8192 B

// 512 threads: 2 chunks of 16B per thread per tile
#define STAGE_K(buf, kv0)                                                          \
  {                                                                                \
    _Pragma("unroll")                                                              \
    for (int p = 0; p < 2; ++p) {                                                  \
      int chunk = p * 512 + t;                                                     \
      int row = chunk >> 4, cb = (chunk & 15) << 4;                                \
      __builtin_amdgcn_global_load_lds(                                            \
        (const __attribute__((address_space(1))) void*)                            \
            (Kg + (size_t)((kv0) + row) * 6144 + (cb ^ ((row & 7) << 4))),         \
        (__attribute__((address_space(3))) void*)(smem + (buf) * 16384 + chunk * 16),\
        16, 0, 0);                                                                 \
    }                                                                              \
  }
#define STAGE_V(buf, kv0)                                                          \
  {                                                                                \
    _Pragma("unroll")                                                              \
    for (int p = 0; p < 2; ++p) {                                                  \
      int chunk = p * 512 + t;                                                     \
      int row = chunk >> 3, cb = (chunk & 7) << 4;                                 \
      __builtin_amdgcn_global_load_lds(                                            \
        (const __attribute__((address_space(1))) void*)                            \
            (Vg + (size_t)row * 8192 + (size_t)(kv0) * 2 + (cb ^ ((row & 7) << 4))),\
        (__attribute__((address_space(3))) void*)(smem + 32768 + (buf) * 16384 + chunk * 16),\
        16, 0, 0);                                                                 \
    }                                                                              \
  }

  bf16x8 onesf;
  #pragma unroll
  for (int j = 0; j < 8; ++j) onesf[j] = (bf16_t)1.0f;

  for (int ph = 0; ph < 2; ++ph) {
    const int xt = ph ? 31 - (int)blockIdx.x : (int)blockIdx.x;   // pair {x, 31-x}
    const int q0b = xt * 128;
    const int q0w = q0b + wq * 32;         // this wave's 32 q-rows
    const int nIter = 2 * xt + 2;

    // Q fragments for 2 subtiles
    bf16x8 qf[2][4];
    #pragma unroll
    for (int sub = 0; sub < 2; ++sub) {
      const bf16_t* qp = QKVb + (size_t)(q0w + sub * 16 + lr) * LDQ + h * 128 + lh * 8;
      #pragma unroll
      for (int kc = 0; kc < 4; ++kc) qf[sub][kc] = *reinterpret_cast<const bf16x8*>(qp + kc * 32);
    }
    __builtin_amdgcn_sched_barrier(0);
    STAGE_K(0, 0);
    STAGE_V(0, 0);
    __builtin_amdgcn_sched_barrier(0);
    STAGE_K(1, 64);     // nIter >= 2 always
    STAGE_V(1, 64);
    __builtin_amdgcn_sched_barrier(0);

    f32x4 oacc[2][8] = {};
    f32x4 lacc[2] = {};

    // one KV-tile step; this wave handles keys [kv0+g*32, kv0+g*32+32)
    auto body = [&](int it, bool masked) {
      const int cur = it & 1;
      const int kv0 = it * 64;
      if (it + 1 < nIter) { asm volatile("s_waitcnt vmcnt(4)" ::: "memory"); }
      else                { asm volatile("s_waitcnt vmcnt(0)" ::: "memory"); }
      __builtin_amdgcn_s_barrier();
      __builtin_amdgcn_sched_barrier(0);

      // ---- S^T = K Q^T on this group's 32 keys ----
      const char* kb = smem + cur * 16384;
      f32x4 s[2][2] = {};    // [sub][n2]
      __builtin_amdgcn_s_setprio(1);
      #pragma unroll
      for (int n2 = 0; n2 < 2; ++n2) {
        const int row = g * 32 + n2 * 16 + lr;
        const int sw = (row & 7) << 4;
        #pragma unroll
        for (int kc = 0; kc < 4; ++kc) {
          bf16x8 kf = *reinterpret_cast<const bf16x8*>(kb + row * 256 + ((kc * 64 + lh * 16) ^ sw));
          s[0][n2] = __builtin_amdgcn_mfma_f32_16x16x32_bf16(kf, qf[0][kc], s[0][n2], 0, 0, 0);
          s[1][n2] = __builtin_amdgcn_mfma_f32_16x16x32_bf16(kf, qf[1][kc], s[1][n2], 0, 0, 0);
        }
      }
      __builtin_amdgcn_s_setprio(0);

      // ---- P = exp2(S) in registers; PV A-frag elems [n2*4+r] <- key n2*16+lh*4+r ----
      bf16x8 pa[2];
      #pragma unroll
      for (int sub = 0; sub < 2; ++sub) {
        const int qs = q0w + sub * 16;
        const bool needM = masked && (kv0 + g * 32 + 31 > qs);
        bf16x8 v;
        #pragma unroll
        for (int n2 = 0; n2 < 2; ++n2) {
          #pragma unroll
          for (int r = 0; r < 4; ++r) {
            float p = exp2f(s[sub][n2][r]);
            if (needM && (kv0 + g * 32 + n2 * 16 + lh * 4 + r > qs + lr)) p = 0.f;
            v[n2 * 4 + r] = (bf16_t)p;
          }
        }
        pa[sub] = v;
      }
      // partial row sums over this key-half (exact; merged across groups later)
      lacc[0] = __builtin_amdgcn_mfma_f32_16x16x32_bf16(pa[0], onesf, lacc[0], 0, 0, 0);
      lacc[1] = __builtin_amdgcn_mfma_f32_16x16x32_bf16(pa[1], onesf, lacc[1], 0, 0, 0);

      // ---- O += P V over this key-half: V-frag = 2x b64 per d-block ----
      const char* vb0 = smem + 32768 + cur * 16384;
      __builtin_amdgcn_s_setprio(1);
      #pragma unroll
      for (int nb = 0; nb < 8; ++nb) {
        const int row = nb * 16 + lr;
        const int sw2 = (row & 7) << 4;
        const char* vb = vb0 + row * 128;
        bf16x4 lo = *reinterpret_cast<const bf16x4*>(vb + ((g * 64 + lh * 8) ^ sw2));
        bf16x4 hi = *reinterpret_cast<const bf16x4*>(vb + ((g * 64 + 32 + lh * 8) ^ sw2));
        bf16x8 vf = __builtin_shufflevector(lo, hi, 0, 1, 2, 3, 4, 5, 6, 7);
        oacc[0][nb] = __builtin_amdgcn_mfma_f32_16x16x32_bf16(pa[0], vf, oacc[0][nb], 0, 0, 0);
        oacc[1][nb] = __builtin_amdgcn_mfma_f32_16x16x32_bf16(pa[1], vf, oacc[1][nb], 0, 0, 0);
      }
      __builtin_amdgcn_s_setprio(0);

      // ---- all waves done reading buf cur -> refill it for tile it+2 ----
      __builtin_amdgcn_sched_barrier(0);
      __builtin_amdgcn_s_barrier();
      __builtin_amdgcn_sched_barrier(0);
      if (it + 2 < nIter) { STAGE_K(cur, kv0 + 128); STAGE_V(cur, kv0 + 128); }
    };

    for (int it = 0; it < nIter - 2; ++it) body(it, false);   // unmasked main loop
    body(nIter - 2, true);                                    // diagonal band
    body(nIter - 1, true);

    // ---- merge key-half partials through (now-dead) LDS ----
    bf16_t* mO = (bf16_t*)smem;              // [4][32][128] bf16 = 32KB
    float*  mL = (float*)(smem + 32768);     // [4][32] f32
    if (g == 1) {
      #pragma unroll
      for (int sub = 0; sub < 2; ++sub) {
        #pragma unroll
        for (int nb = 0; nb < 8; ++nb)
          #pragma unroll
          for (int r = 0; r < 4; ++r)
            mO[((wq * 32 + sub * 16 + lh * 4 + r) << 7) + nb * 16 + lr] = (bf16_t)oacc[sub][nb][r];
        if (lr == 0)
          #pragma unroll
          for (int r = 0; r < 4; ++r) mL[wq * 32 + sub * 16 + lh * 4 + r] = lacc[sub][r];
      }
    }
    __syncthreads();
    if (g == 0) {
      #pragma unroll
      for (int sub = 0; sub < 2; ++sub) {
        f32x4 linv;
        #pragma unroll
        for (int r = 0; r < 4; ++r)
          linv[r] = 1.0f / (lacc[sub][r] + mL[wq * 32 + sub * 16 + lh * 4 + r]);
        #pragma unroll
        for (int nb = 0; nb < 8; ++nb) {
          #pragma unroll
          for (int r = 0; r < 4; ++r) {
            float o1 = (float)mO[((wq * 32 + sub * 16 + lh * 4 + r) << 7) + nb * 16 + lr];
            float v = (oacc[sub][nb][r] + o1) * linv[r];
            Ob[(size_t)(q0w + sub * 16 + lh * 4 + r) * 2048 + h * 128 + nb * 16 + lr] = (bf16_t)v;
          }
        }
      }
    }
    __syncthreads();   // protect merge region from next phase's staging
  }
#undef STAGE_K
#undef STAGE_V
}

extern "C" void kernel_launch(void* const* d_in, const int* in_sizes, int n_in,
                              void* d_out, int out_size, void* d_ws, size_t ws_size,
                              hipStream_t stream) {
  const float* seq   = (const float*)d_in[0];
  const float* Wq_w  = (const float*)d_in[2];
  const float* Wq_b  = (const float*)d_in[3];
  const float* Wkv_w = (const float*)d_in[4];
  const float* Wkv_b = (const float*)d_in[5];
  const float* Wo_w  = (const float*)d_in[6];
  const float* Wo_b  = (const float*)d_in[7];

  float* out   = (float*)d_out;
  float* kvout = out + (size_t)4096 * 2048;

  char* ws = (char*)d_ws;
  bf16_t* seqb = (bf16_t*)ws;                          // [4096][2048] (reused as Ob)
  bf16_t* wqkv = (bf16_t*)(ws + 16777216);             // [3072][2048]
  bf16_t* wob  = (bf16_t*)(ws + 29360128);             // [2048][2048]
  bf16_t* qkvb = (bf16_t*)(ws + 37748736);             // [4096][3072]
  bf16_t* vt   = (bf16_t*)(ws + 62914560);             // [4][128][4096]
  bf16_t* ob   = seqb;

  cast_kernel<<<4096, 256, 0, stream>>>(seq, seqb, 1048576);
  cast_kernel<<<2048, 256, 0, stream>>>(Wq_w, wqkv, 524288);
  cast_kernel<<<1024, 256, 0, stream>>>(Wkv_w, wqkv + 4194304, 262144);
  cast_kernel<<<2048, 256, 0, stream>>>(Wo_w, wob, 524288);

  gemm_bt<1><<<dim3(32, 24), 256, 0, stream>>>(seqb, wqkv, Wq_b, Wkv_b,
                                               qkvb, kvout, vt, 4096, 3072, 2048);
  attn_kernel<<<dim3(16, 16), 512, 0, stream>>>(qkvb, vt, ob);
  gemm_bt<0><<<dim3(32, 16), 256, 0, stream>>>(ob, wob, Wo_b, nullptr,
                                               out, nullptr, nullptr, 4096, 2048, 2048);
}